// Round 4
// baseline (817.377 us; speedup 1.0000x reference)
//
#include <hip/hip_runtime.h>

// Shape: (B=2, C=1, D=160, H=192, W=160) fp32. win = 9 (per-dim), win_size = 9 (faithful bug).
#define B_ 2
#define D_ 160
#define H_ 192
#define W_ 160
#define HW_ (H_ * W_)                       // 30720
#define NV_ ((long long)B_ * D_ * H_ * W_)  // 9,830,400

__global__ void k_zero(double* acc) { *acc = 0.0; }

__device__ __forceinline__ float prod_c(int c, float a, float b) {
    switch (c) {
        case 0:  return a;
        case 1:  return b;
        case 2:  return a * a;
        case 3:  return b * b;
        default: return a * b;
    }
}

// ---------------------------------------------------------------------------
// P1: 9-window sum along Y of product-map c, for one z-slab of one batch.
// One thread per (c, zl, x) column; marches y with a 9-slot register ring
// (inner loop of 9 fully unrolled -> static ring indices, no scratch).
// A layout: [c][zl][y][x], c-stride = ZS*HW.
// ---------------------------------------------------------------------------
__global__ void p1_ysum(const float* __restrict__ I, const float* __restrict__ J,
                        float* __restrict__ A, int b, int zlo, int ZS) {
    const int col = blockIdx.x * blockDim.x + threadIdx.x;
    const int ncol = 5 * ZS * W_;
    if (col >= ncol) return;
    const int x  = col % W_;
    const int t  = col / W_;
    const int zl = t % ZS;
    const int c  = t / ZS;

    const float* Ip = I + ((size_t)(b * D_ + zlo + zl) * H_) * W_ + x;
    const float* Jp = J + ((size_t)(b * D_ + zlo + zl) * H_) * W_ + x;
    float* out = A + ((size_t)c * ZS + zl) * HW_ + x;

    float ring[9];
    ring[0] = 0.f; ring[1] = 0.f; ring[2] = 0.f; ring[3] = 0.f; ring[4] = 0.f;
    float s = 0.f;
#pragma unroll
    for (int j = 0; j < 4; ++j) {
        const float v = prod_c(c, Ip[(size_t)j * W_], Jp[(size_t)j * W_]);
        ring[5 + j] = v;
        s += v;
    }
    for (int y0 = 0; y0 < 22; ++y0) {   // 22*9 = 198 >= 192
#pragma unroll
        for (int j = 0; j < 9; ++j) {
            const int y = y0 * 9 + j;
            if (y < H_) {
                const int yi = y + 4;
                float inc = 0.f;
                if (yi < H_) inc = prod_c(c, Ip[(size_t)yi * W_], Jp[(size_t)yi * W_]);
                s += inc - ring[j];
                ring[j] = inc;
                out[(size_t)y * W_] = s;
            }
        }
    }
}

// ---------------------------------------------------------------------------
// P2: 9-window sum along Z. One thread per (c, pixel) column; marches zl.
// In  A: [c][zl][y][x]  (zl in [0,ZS), absolute z = zlo + zl)
// Out Bv: [c][zo][y][x] (zo in [0,ZC)); zoff = z0 - zlo.
// ---------------------------------------------------------------------------
__global__ void p2_zsum(const float* __restrict__ A, float* __restrict__ Bv,
                        int ZS, int zoff, int ZC) {
    const int col = blockIdx.x * blockDim.x + threadIdx.x;
    if (col >= 5 * HW_) return;
    const int pix = col % HW_;
    const int c   = col / HW_;

    const float* in = A + (size_t)c * ZS * HW_ + pix;
    float* out = Bv + (size_t)c * ZC * HW_ + pix;

    float ring[9];
    ring[0] = 0.f;
    float s = 0.f;
#pragma unroll
    for (int j = 0; j < 8; ++j) {       // values v(zoff-4 .. zoff+3)
        const int zl = zoff - 4 + j;
        float v = 0.f;
        if (zl >= 0 && zl < ZS) v = in[(size_t)zl * HW_];
        ring[1 + j] = v;
        s += v;
    }
    const int nmac = (ZC + 8) / 9;
    for (int p0 = 0; p0 < nmac; ++p0) {
#pragma unroll
        for (int j = 0; j < 9; ++j) {
            const int p = p0 * 9 + j;
            if (p < ZC) {
                const int zi = zoff + p + 4;
                float inc = 0.f;
                if (zi < ZS) inc = in[(size_t)zi * HW_];
                s += inc - ring[j];
                ring[j] = inc;
                out[(size_t)p * HW_] = s;
            }
        }
    }
}

// ---------------------------------------------------------------------------
// P3: 9-window sum along X (9 shifted coalesced loads per map, L1-resident),
// then cc + block reduction + one double atomic per block.
// ---------------------------------------------------------------------------
__global__ void p3_cc(const float* __restrict__ Bv, double* __restrict__ acc, int ZC) {
    const long long nvox = (long long)ZC * HW_;
    const long long idx = (long long)blockIdx.x * blockDim.x + threadIdx.x;
    float local = 0.f;
    if (idx < nvox) {
        const int x = (int)(idx % W_);
        const size_t row = (size_t)(idx - x);
        const size_t cs = (size_t)ZC * HW_;
        float S[5];
#pragma unroll
        for (int c = 0; c < 5; ++c) {
            const float* p = Bv + c * cs + row;
            float s = 0.f;
#pragma unroll
            for (int d = -4; d <= 4; ++d) {
                const int xx = x + d;
                if (xx >= 0 && xx < W_) s += p[xx];
            }
            S[c] = s;
        }
        const float inv9 = 1.0f / 9.0f;
        const float cross = S[4] - S[1] * S[0] * inv9;
        const float iv    = S[2] - S[0] * S[0] * inv9;
        const float jv    = S[3] - S[1] * S[1] * inv9;
        local = cross * cross / (iv * jv + 1e-5f);
    }
    __shared__ float red[256];
    red[threadIdx.x] = local;
    __syncthreads();
    for (int off = 128; off > 0; off >>= 1) {
        if (threadIdx.x < off) red[threadIdx.x] += red[threadIdx.x + off];
        __syncthreads();
    }
    if (threadIdx.x == 0) atomicAdd(acc, (double)red[0]);
}

// ---------------------------------------------------------------------------
// Fallback (workspace too small for slabs): direct clipped 9x9x9 window sums
// per voxel. Slow but exact and needs no scratch arrays beyond 8 bytes.
// ---------------------------------------------------------------------------
__global__ void p_direct(const float* __restrict__ I, const float* __restrict__ J,
                         double* __restrict__ acc) {
    const long long idx = (long long)blockIdx.x * blockDim.x + threadIdx.x;
    float local = 0.f;
    if (idx < NV_) {
        const int x = (int)(idx % W_);
        long long t = idx / W_;
        const int y = (int)(t % H_);
        t /= H_;
        const int z = (int)(t % D_);
        const int b = (int)(t / D_);
        const int z0 = max(z - 4, 0), z1 = min(z + 4, D_ - 1);
        const int y0 = max(y - 4, 0), y1 = min(y + 4, H_ - 1);
        const int x0 = max(x - 4, 0), x1 = min(x + 4, W_ - 1);
        float sI = 0.f, sJ = 0.f, sI2 = 0.f, sJ2 = 0.f, sIJ = 0.f;
        for (int zz = z0; zz <= z1; ++zz) {
            for (int yy = y0; yy <= y1; ++yy) {
                const size_t row = ((size_t)(b * D_ + zz) * H_ + yy) * W_;
                for (int xx = x0; xx <= x1; ++xx) {
                    const float a = I[row + xx];
                    const float bb = J[row + xx];
                    sI += a; sJ += bb; sI2 += a * a; sJ2 += bb * bb; sIJ += a * bb;
                }
            }
        }
        const float inv9 = 1.0f / 9.0f;
        const float cross = sIJ - sJ * sI * inv9;
        const float iv    = sI2 - sI * sI * inv9;
        const float jv    = sJ2 - sJ * sJ * inv9;
        local = cross * cross / (iv * jv + 1e-5f);
    }
    __shared__ float red[256];
    red[threadIdx.x] = local;
    __syncthreads();
    for (int off = 128; off > 0; off >>= 1) {
        if (threadIdx.x < off) red[threadIdx.x] += red[threadIdx.x + off];
        __syncthreads();
    }
    if (threadIdx.x == 0) atomicAdd(acc, (double)red[0]);
}

__global__ void k_final(const double* __restrict__ acc, float* __restrict__ out) {
    out[0] = (float)(-(*acc) / (double)NV_);
}

extern "C" void kernel_launch(void* const* d_in, const int* in_sizes, int n_in,
                              void* d_out, int out_size, void* d_ws, size_t ws_size,
                              hipStream_t stream) {
    const float* I = (const float*)d_in[0];  // y_true
    const float* J = (const float*)d_in[1];  // y_pred
    float* out = (float*)d_out;

    // choose the largest z-chunk the workspace can hold (exact results for any)
    const int zc_opts[5] = {160, 80, 40, 20, 10};
    int ZC = 0;
    for (int i = 0; i < 5; ++i) {
        const int zc = zc_opts[i];
        const int zsmax = (zc + 8 < D_) ? zc + 8 : D_;
        const size_t need = 1024 + (size_t)5 * zsmax * HW_ * 4 + (size_t)5 * zc * HW_ * 4;
        if (need <= ws_size) { ZC = zc; break; }
    }

    if (ZC == 0) {
        // workspace too small for the separable path — direct fallback.
        if (ws_size >= sizeof(double)) {
            double* acc = (double*)d_ws;
            k_zero<<<1, 1, 0, stream>>>(acc);
            p_direct<<<(int)((NV_ + 255) / 256), 256, 0, stream>>>(I, J, acc);
            k_final<<<1, 1, 0, stream>>>(acc, out);
        }
        return;
    }

    const int ZSmax = (ZC + 8 < D_) ? ZC + 8 : D_;
    double* acc = (double*)d_ws;
    float* A  = (float*)((char*)d_ws + 1024);
    float* Bv = A + (size_t)5 * ZSmax * HW_;

    k_zero<<<1, 1, 0, stream>>>(acc);

    for (int b = 0; b < B_; ++b) {
        for (int z0 = 0; z0 < D_; z0 += ZC) {
            const int zlo = (z0 - 4 > 0) ? z0 - 4 : 0;
            const int zhi = (z0 + ZC + 4 < D_) ? z0 + ZC + 4 : D_;
            const int ZS = zhi - zlo;
            const int zoff = z0 - zlo;

            const int ncol1 = 5 * ZS * W_;
            p1_ysum<<<(ncol1 + 255) / 256, 256, 0, stream>>>(I, J, A, b, zlo, ZS);

            const int ncol2 = 5 * HW_;
            p2_zsum<<<(ncol2 + 255) / 256, 256, 0, stream>>>(A, Bv, ZS, zoff, ZC);

            const long long nvox = (long long)ZC * HW_;
            p3_cc<<<(int)((nvox + 255) / 256), 256, 0, stream>>>(Bv, acc, ZC);
        }
    }

    k_final<<<1, 1, 0, stream>>>(acc, out);
}

// Round 5
// 191.251 us; speedup vs baseline: 4.2739x; 4.2739x over previous
//
#include <hip/hip_runtime.h>

// Shape: (B=2, C=1, D=160, H=192, W=160) fp32. win=9/dim, win_size=9 (faithful bug).
#define B_ 2
#define D_ 160
#define H_ 192
#define W_ 160
#define HW_ (H_ * W_)                        // 30720
#define DHW_ (D_ * HW_)                      // 4,915,200
#define NV_ ((long long)B_ * D_ * H_ * W_)   // 9,830,400

#define YCH 24
#define NYC (H_ / YCH)     // 8
#define ZCH 32
#define NZC (D_ / ZCH)     // 5
#define ROWS 2

__global__ void k_zero(double* acc) { *acc = 0.0; }

// ---------------------------------------------------------------------------
// K1: y-direction 9-window sums of the 5 product maps, all channels per
// thread, two-pointer sliding window (trailing re-read is L1-hit).
// One thread per (b, z, y-chunk, x). A layout: [(b*5+c)*D + z][y][x].
// ---------------------------------------------------------------------------
__global__ void k1_ysum(const float* __restrict__ I, const float* __restrict__ J,
                        float* __restrict__ A) {
    const int g = blockIdx.x * blockDim.x + threadIdx.x;
    const int ncol = B_ * D_ * NYC * W_;     // 409,600
    if (g >= ncol) return;
    const int x  = g % W_;
    int t = g / W_;
    const int yc = t % NYC;  t /= NYC;
    const int z  = t % D_;
    const int b  = t / D_;
    const int y0 = yc * YCH;

    const size_t in_base = ((size_t)(b * D_ + z) * H_) * W_ + x;
    const float* Ip = I + in_base;
    const float* Jp = J + in_base;
    float* Ap = A + (size_t)(b * 5) * DHW_ + (size_t)z * HW_ + x;

    float s0 = 0.f, s1 = 0.f, s2 = 0.f, s3 = 0.f, s4 = 0.f;
#pragma unroll
    for (int j = 0; j < 8; ++j) {            // prime window [y0-4, y0+3]
        const int yin = y0 - 4 + j;
        if (yin >= 0) {                      // yin < H_ always (y0+3 <= 171)
            const float a = Ip[(size_t)yin * W_];
            const float bb = Jp[(size_t)yin * W_];
            s0 += a; s1 += bb; s2 += a * a; s3 += bb * bb; s4 += a * bb;
        }
    }
#pragma unroll 4
    for (int k = 0; k < YCH; ++k) {
        const int yi = y0 + k + 4;           // leading edge
        if (yi < H_) {
            const float a = Ip[(size_t)yi * W_];
            const float bb = Jp[(size_t)yi * W_];
            s0 += a; s1 += bb; s2 += a * a; s3 += bb * bb; s4 += a * bb;
        }
        const int yo = y0 + k - 5;           // trailing edge
        if (yo >= 0) {
            const float a = Ip[(size_t)yo * W_];
            const float bb = Jp[(size_t)yo * W_];
            s0 -= a; s1 -= bb; s2 -= a * a; s3 -= bb * bb; s4 -= a * bb;
        }
        const size_t o = (size_t)(y0 + k) * W_;
        Ap[o]              = s0;
        Ap[o + 1 * (size_t)DHW_] = s1;
        Ap[o + 2 * (size_t)DHW_] = s2;
        Ap[o + 3 * (size_t)DHW_] = s3;
        Ap[o + 4 * (size_t)DHW_] = s4;
    }
}

// ---------------------------------------------------------------------------
// K2: fused z-window sum + x-window sum (via LDS) + cc + reduction.
// Block = ROWS(2) rows x W(160) = 320 threads, marching a z-chunk of 32.
// Two-pointer z-window per channel; per step dump s[5] into double-buffered
// LDS row, one barrier, 45 LDS taps for the x-window, cc, accumulate.
// ---------------------------------------------------------------------------
__global__ void k2_zxcc(const float* __restrict__ A, double* __restrict__ acc) {
    __shared__ float sbuf[2][ROWS][5][W_];   // 12.8 KB
    __shared__ float red[512];
    const int blk = blockIdx.x;
    const int zc  = blk % NZC;
    const int rp  = blk / NZC;               // 0 .. B*H/ROWS-1 = 0..191
    const int tid = threadIdx.x;             // 0..319
    const int r   = tid / W_;                // 0/1
    const int x   = tid - r * W_;
    const int gy  = rp * ROWS + r;           // 0..383
    const int b   = gy / H_;
    const int yy  = gy - b * H_;
    const int z0  = zc * ZCH;

    const float* Ap = A + (size_t)(b * 5) * DHW_ + (size_t)yy * W_ + x;

    float s[5];
#pragma unroll
    for (int c = 0; c < 5; ++c) s[c] = 0.f;
#pragma unroll
    for (int j = 0; j < 8; ++j) {            // prime window [z0-4, z0+3]
        const int zi = z0 - 4 + j;           // zi < D_ always (z0+3 <= 131)
        if (zi >= 0) {
#pragma unroll
            for (int c = 0; c < 5; ++c)
                s[c] += Ap[(size_t)c * DHW_ + (size_t)zi * HW_];
        }
    }

    float local = 0.f;
    for (int k = 0; k < ZCH; ++k) {
        const int zi = z0 + k + 4;
        if (zi < D_) {
#pragma unroll
            for (int c = 0; c < 5; ++c)
                s[c] += Ap[(size_t)c * DHW_ + (size_t)zi * HW_];
        }
        const int zo = z0 + k - 5;
        if (zo >= 0) {
#pragma unroll
            for (int c = 0; c < 5; ++c)
                s[c] -= Ap[(size_t)c * DHW_ + (size_t)zo * HW_];
        }
        const int p = k & 1;
#pragma unroll
        for (int c = 0; c < 5; ++c) sbuf[p][r][c][x] = s[c];
        __syncthreads();
        float S[5];
#pragma unroll
        for (int c = 0; c < 5; ++c) {
            float tt = 0.f;
#pragma unroll
            for (int d = -4; d <= 4; ++d) {
                const int xx = x + d;
                if (xx >= 0 && xx < W_) tt += sbuf[p][r][c][xx];
            }
            S[c] = tt;
        }
        const float inv9 = 1.0f / 9.0f;
        const float cross = S[4] - S[1] * S[0] * inv9;
        const float iv    = S[2] - S[0] * S[0] * inv9;
        const float jv    = S[3] - S[1] * S[1] * inv9;
        local += cross * cross / (iv * jv + 1e-5f);
    }

    red[tid] = local;
    if (tid < 192) red[320 + tid] = 0.f;
    __syncthreads();
    for (int off = 256; off > 0; off >>= 1) {
        if (tid < off) red[tid] += red[tid + off];
        __syncthreads();
    }
    if (tid == 0) atomicAdd(acc, (double)red[0]);
}

// ---------------------------------------------------------------------------
// Fallback (workspace too small): direct clipped 9x9x9 sums per voxel.
// ---------------------------------------------------------------------------
__global__ void p_direct(const float* __restrict__ I, const float* __restrict__ J,
                         double* __restrict__ acc) {
    const long long idx = (long long)blockIdx.x * blockDim.x + threadIdx.x;
    float local = 0.f;
    if (idx < NV_) {
        const int x = (int)(idx % W_);
        long long t = idx / W_;
        const int y = (int)(t % H_);
        t /= H_;
        const int z = (int)(t % D_);
        const int b = (int)(t / D_);
        const int z0 = max(z - 4, 0), z1 = min(z + 4, D_ - 1);
        const int y0 = max(y - 4, 0), y1 = min(y + 4, H_ - 1);
        const int x0 = max(x - 4, 0), x1 = min(x + 4, W_ - 1);
        float sI = 0.f, sJ = 0.f, sI2 = 0.f, sJ2 = 0.f, sIJ = 0.f;
        for (int zz = z0; zz <= z1; ++zz)
            for (int yy = y0; yy <= y1; ++yy) {
                const size_t row = ((size_t)(b * D_ + zz) * H_ + yy) * W_;
                for (int xx = x0; xx <= x1; ++xx) {
                    const float a = I[row + xx];
                    const float bb = J[row + xx];
                    sI += a; sJ += bb; sI2 += a * a; sJ2 += bb * bb; sIJ += a * bb;
                }
            }
        const float inv9 = 1.0f / 9.0f;
        const float cross = sIJ - sJ * sI * inv9;
        const float iv    = sI2 - sI * sI * inv9;
        const float jv    = sJ2 - sJ * sJ * inv9;
        local = cross * cross / (iv * jv + 1e-5f);
    }
    __shared__ float red[256];
    red[threadIdx.x] = local;
    __syncthreads();
    for (int off = 128; off > 0; off >>= 1) {
        if (threadIdx.x < off) red[threadIdx.x] += red[threadIdx.x + off];
        __syncthreads();
    }
    if (threadIdx.x == 0) atomicAdd(acc, (double)red[0]);
}

__global__ void k_final(const double* __restrict__ acc, float* __restrict__ out) {
    out[0] = (float)(-(*acc) / (double)NV_);
}

extern "C" void kernel_launch(void* const* d_in, const int* in_sizes, int n_in,
                              void* d_out, int out_size, void* d_ws, size_t ws_size,
                              hipStream_t stream) {
    const float* I = (const float*)d_in[0];  // y_true
    const float* J = (const float*)d_in[1];  // y_pred
    float* out = (float*)d_out;

    const size_t needA = (size_t)5 * B_ * DHW_ * sizeof(float);  // 196.6 MB
    if (ws_size >= 1024 + needA) {
        double* acc = (double*)d_ws;
        float* A = (float*)((char*)d_ws + 1024);
        k_zero<<<1, 1, 0, stream>>>(acc);
        const int ncol = B_ * D_ * NYC * W_;
        k1_ysum<<<(ncol + 255) / 256, 256, 0, stream>>>(I, J, A);
        k2_zxcc<<<NZC * (B_ * H_ / ROWS), ROWS * W_, 0, stream>>>(A, acc);
        k_final<<<1, 1, 0, stream>>>(acc, out);
    } else if (ws_size >= sizeof(double)) {
        double* acc = (double*)d_ws;
        k_zero<<<1, 1, 0, stream>>>(acc);
        p_direct<<<(int)((NV_ + 255) / 256), 256, 0, stream>>>(I, J, acc);
        k_final<<<1, 1, 0, stream>>>(acc, out);
    }
}

// Round 6
// 161.261 us; speedup vs baseline: 5.0687x; 1.1860x over previous
//
#include <hip/hip_runtime.h>

// Shape: (B=2, C=1, D=160, H=192, W=160) fp32. win=9/dim, win_size=9 (faithful bug).
#define B_ 2
#define D_ 160
#define H_ 192
#define W_ 160
#define W4_ (W_ / 4)                         // 40
#define HW_ (H_ * W_)                        // 30720
#define DHW_ (D_ * HW_)                      // 4,915,200
#define NV_ ((long long)B_ * D_ * H_ * W_)   // 9,830,400

#define YCH 24
#define NYC (H_ / YCH)     // 8

#define ROWS2 8
#define ZCH2 16
#define NZC2 (D_ / ZCH2)   // 10
#define PAD 4
#define LROW (W_ + 2 * PAD)  // 168

__global__ void k_zero(double* acc) { *acc = 0.0; }

__device__ __forceinline__ void add4(float4& d, const float4 v) {
    d.x += v.x; d.y += v.y; d.z += v.z; d.w += v.w;
}
__device__ __forceinline__ void sub4(float4& d, const float4 v) {
    d.x -= v.x; d.y -= v.y; d.z -= v.z; d.w -= v.w;
}

// ---------------------------------------------------------------------------
// K1: y-direction 9-window sums of the 5 product maps, float4 along x.
// One thread per (b, z, y-chunk, x4). A layout: [(b*5+c)*D + z][y][x].
// ---------------------------------------------------------------------------
__global__ void k1_ysum(const float* __restrict__ I, const float* __restrict__ J,
                        float* __restrict__ A) {
    const int g = blockIdx.x * blockDim.x + threadIdx.x;
    const int ncol = B_ * D_ * NYC * W4_;    // 102,400
    if (g >= ncol) return;
    const int l  = g % W4_;
    int t = g / W4_;
    const int yc = t % NYC;  t /= NYC;
    const int z  = t % D_;
    const int b  = t / D_;
    const int y0 = yc * YCH;
    const int x4 = l * 4;

    const float* Ipf = I + ((size_t)(b * D_ + z) * H_) * W_ + x4;
    const float* Jpf = J + ((size_t)(b * D_ + z) * H_) * W_ + x4;
    float* Ap = A + (size_t)(b * 5) * DHW_ + (size_t)z * HW_ + x4;

    float4 s0 = make_float4(0,0,0,0), s1 = s0, s2 = s0, s3 = s0, s4 = s0;
#pragma unroll
    for (int j = 0; j < 8; ++j) {            // prime window [y0-4, y0+3]
        const int yin = y0 - 4 + j;          // yin <= y0+3 <= 171 < H_ always
        if (yin >= 0) {
            const float4 a  = *(const float4*)(Ipf + (size_t)yin * W_);
            const float4 bb = *(const float4*)(Jpf + (size_t)yin * W_);
            s0.x += a.x;        s0.y += a.y;        s0.z += a.z;        s0.w += a.w;
            s1.x += bb.x;       s1.y += bb.y;       s1.z += bb.z;       s1.w += bb.w;
            s2.x += a.x*a.x;    s2.y += a.y*a.y;    s2.z += a.z*a.z;    s2.w += a.w*a.w;
            s3.x += bb.x*bb.x;  s3.y += bb.y*bb.y;  s3.z += bb.z*bb.z;  s3.w += bb.w*bb.w;
            s4.x += a.x*bb.x;   s4.y += a.y*bb.y;   s4.z += a.z*bb.z;   s4.w += a.w*bb.w;
        }
    }
#pragma unroll 4
    for (int k = 0; k < YCH; ++k) {
        const int yi = y0 + k + 4;           // leading edge
        if (yi < H_) {
            const float4 a  = *(const float4*)(Ipf + (size_t)yi * W_);
            const float4 bb = *(const float4*)(Jpf + (size_t)yi * W_);
            s0.x += a.x;        s0.y += a.y;        s0.z += a.z;        s0.w += a.w;
            s1.x += bb.x;       s1.y += bb.y;       s1.z += bb.z;       s1.w += bb.w;
            s2.x += a.x*a.x;    s2.y += a.y*a.y;    s2.z += a.z*a.z;    s2.w += a.w*a.w;
            s3.x += bb.x*bb.x;  s3.y += bb.y*bb.y;  s3.z += bb.z*bb.z;  s3.w += bb.w*bb.w;
            s4.x += a.x*bb.x;   s4.y += a.y*bb.y;   s4.z += a.z*bb.z;   s4.w += a.w*bb.w;
        }
        const int yo = y0 + k - 5;           // trailing edge
        if (yo >= 0) {
            const float4 a  = *(const float4*)(Ipf + (size_t)yo * W_);
            const float4 bb = *(const float4*)(Jpf + (size_t)yo * W_);
            s0.x -= a.x;        s0.y -= a.y;        s0.z -= a.z;        s0.w -= a.w;
            s1.x -= bb.x;       s1.y -= bb.y;       s1.z -= bb.z;       s1.w -= bb.w;
            s2.x -= a.x*a.x;    s2.y -= a.y*a.y;    s2.z -= a.z*a.z;    s2.w -= a.w*a.w;
            s3.x -= bb.x*bb.x;  s3.y -= bb.y*bb.y;  s3.z -= bb.z*bb.z;  s3.w -= bb.w*bb.w;
            s4.x -= a.x*bb.x;   s4.y -= a.y*bb.y;   s4.z -= a.z*bb.z;   s4.w -= a.w*bb.w;
        }
        const size_t o = (size_t)(y0 + k) * W_;
        *(float4*)(Ap + o)                      = s0;
        *(float4*)(Ap + o + 1 * (size_t)DHW_)   = s1;
        *(float4*)(Ap + o + 2 * (size_t)DHW_)   = s2;
        *(float4*)(Ap + o + 3 * (size_t)DHW_)   = s3;
        *(float4*)(Ap + o + 4 * (size_t)DHW_)   = s4;
    }
}

// ---------------------------------------------------------------------------
// K2: fused z-window sum (float4 running) + x-window (3x ds_read_b128 per
// channel over a padded LDS row) + cc + reduction.
// Block = 8 rows x 40 lanes (320 thr); each thread owns 4 x-columns and
// marches a z-chunk of 16. One barrier per z-step (double-buffered LDS).
// ---------------------------------------------------------------------------
__global__ void k2_zxcc(const float* __restrict__ A, double* __restrict__ acc) {
    __shared__ float sbuf[2][ROWS2][5][LROW];   // 53.76 KB
    __shared__ float red[512];
    const int tid = threadIdx.x;             // 0..319
    const int r   = tid / W4_;               // 0..7
    const int l   = tid - r * W4_;           // 0..39
    const int x4  = l * 4;
    const int blk = blockIdx.x;
    const int zc  = blk % NZC2;
    const int rp  = blk / NZC2;              // 0..47
    const int gy  = rp * ROWS2 + r;          // 0..383  (192%8==0: no b straddle)
    const int b   = gy / H_;
    const int yy  = gy - b * H_;
    const int z0  = zc * ZCH2;

    {   // zero LDS once (pads must be 0; interior overwritten every step)
        float* p = &sbuf[0][0][0][0];
        for (int i = tid; i < 2 * ROWS2 * 5 * LROW; i += ROWS2 * W4_) p[i] = 0.f;
    }
    __syncthreads();

    const float* Abase = A + (size_t)(b * 5) * DHW_ + (size_t)yy * W_ + x4;

    float4 s[5];
#pragma unroll
    for (int c = 0; c < 5; ++c) s[c] = make_float4(0, 0, 0, 0);
#pragma unroll
    for (int j = 0; j < 8; ++j) {            // prime [z0-4, z0+3]; z0+3 <= 147 < D_
        const int zi = z0 - 4 + j;
        if (zi >= 0) {
#pragma unroll
            for (int c = 0; c < 5; ++c)
                add4(s[c], *(const float4*)(Abase + (size_t)c * DHW_ + (size_t)zi * HW_));
        }
    }

    float local = 0.f;
    for (int k = 0; k < ZCH2; ++k) {
        const int zi = z0 + k + 4;
        if (zi < D_) {
#pragma unroll
            for (int c = 0; c < 5; ++c)
                add4(s[c], *(const float4*)(Abase + (size_t)c * DHW_ + (size_t)zi * HW_));
        }
        const int zo = z0 + k - 5;
        if (zo >= 0) {
#pragma unroll
            for (int c = 0; c < 5; ++c)
                sub4(s[c], *(const float4*)(Abase + (size_t)c * DHW_ + (size_t)zo * HW_));
        }
        const int p = k & 1;
#pragma unroll
        for (int c = 0; c < 5; ++c)
            *(float4*)&sbuf[p][r][c][PAD + x4] = s[c];
        __syncthreads();

        float4 S5[5];
#pragma unroll
        for (int c = 0; c < 5; ++c) {
            // storage index of x-window start (x4-4) is PAD + x4 - 4 = x4: aligned.
            const float4 a0 = *(const float4*)&sbuf[p][r][c][x4];
            const float4 a1 = *(const float4*)&sbuf[p][r][c][x4 + 4];
            const float4 a2 = *(const float4*)&sbuf[p][r][c][x4 + 8];
            const float o0 = a0.x + a0.y + a0.z + a0.w + a1.x + a1.y + a1.z + a1.w + a2.x;
            const float o1 = o0 - a0.x + a2.y;
            const float o2 = o1 - a0.y + a2.z;
            const float o3 = o2 - a0.z + a2.w;
            S5[c] = make_float4(o0, o1, o2, o3);
        }
        const float inv9 = 1.0f / 9.0f;
        {
            const float cr = S5[4].x - S5[1].x * S5[0].x * inv9;
            const float iv = S5[2].x - S5[0].x * S5[0].x * inv9;
            const float jv = S5[3].x - S5[1].x * S5[1].x * inv9;
            local += cr * cr / (iv * jv + 1e-5f);
        }
        {
            const float cr = S5[4].y - S5[1].y * S5[0].y * inv9;
            const float iv = S5[2].y - S5[0].y * S5[0].y * inv9;
            const float jv = S5[3].y - S5[1].y * S5[1].y * inv9;
            local += cr * cr / (iv * jv + 1e-5f);
        }
        {
            const float cr = S5[4].z - S5[1].z * S5[0].z * inv9;
            const float iv = S5[2].z - S5[0].z * S5[0].z * inv9;
            const float jv = S5[3].z - S5[1].z * S5[1].z * inv9;
            local += cr * cr / (iv * jv + 1e-5f);
        }
        {
            const float cr = S5[4].w - S5[1].w * S5[0].w * inv9;
            const float iv = S5[2].w - S5[0].w * S5[0].w * inv9;
            const float jv = S5[3].w - S5[1].w * S5[1].w * inv9;
            local += cr * cr / (iv * jv + 1e-5f);
        }
        // single barrier per step is WAR-safe: next iteration writes buffer p^1.
    }

    red[tid] = local;
    if (tid < 192) red[320 + tid] = 0.f;
    __syncthreads();
    for (int off = 256; off > 0; off >>= 1) {
        if (tid < off) red[tid] += red[tid + off];
        __syncthreads();
    }
    if (tid == 0) atomicAdd(acc, (double)red[0]);
}

// ---------------------------------------------------------------------------
// Fallback (workspace too small): direct clipped 9x9x9 sums per voxel.
// ---------------------------------------------------------------------------
__global__ void p_direct(const float* __restrict__ I, const float* __restrict__ J,
                         double* __restrict__ acc) {
    const long long idx = (long long)blockIdx.x * blockDim.x + threadIdx.x;
    float local = 0.f;
    if (idx < NV_) {
        const int x = (int)(idx % W_);
        long long t = idx / W_;
        const int y = (int)(t % H_);
        t /= H_;
        const int z = (int)(t % D_);
        const int b = (int)(t / D_);
        const int z0 = max(z - 4, 0), z1 = min(z + 4, D_ - 1);
        const int y0 = max(y - 4, 0), y1 = min(y + 4, H_ - 1);
        const int x0 = max(x - 4, 0), x1 = min(x + 4, W_ - 1);
        float sI = 0.f, sJ = 0.f, sI2 = 0.f, sJ2 = 0.f, sIJ = 0.f;
        for (int zz = z0; zz <= z1; ++zz)
            for (int yy = y0; yy <= y1; ++yy) {
                const size_t row = ((size_t)(b * D_ + zz) * H_ + yy) * W_;
                for (int xx = x0; xx <= x1; ++xx) {
                    const float a = I[row + xx];
                    const float bb = J[row + xx];
                    sI += a; sJ += bb; sI2 += a * a; sJ2 += bb * bb; sIJ += a * bb;
                }
            }
        const float inv9 = 1.0f / 9.0f;
        const float cross = sIJ - sJ * sI * inv9;
        const float iv    = sI2 - sI * sI * inv9;
        const float jv    = sJ2 - sJ * sJ * inv9;
        local = cross * cross / (iv * jv + 1e-5f);
    }
    __shared__ float red[256];
    red[threadIdx.x] = local;
    __syncthreads();
    for (int off = 128; off > 0; off >>= 1) {
        if (threadIdx.x < off) red[threadIdx.x] += red[threadIdx.x + off];
        __syncthreads();
    }
    if (threadIdx.x == 0) atomicAdd(acc, (double)red[0]);
}

__global__ void k_final(const double* __restrict__ acc, float* __restrict__ out) {
    out[0] = (float)(-(*acc) / (double)NV_);
}

extern "C" void kernel_launch(void* const* d_in, const int* in_sizes, int n_in,
                              void* d_out, int out_size, void* d_ws, size_t ws_size,
                              hipStream_t stream) {
    const float* I = (const float*)d_in[0];  // y_true
    const float* J = (const float*)d_in[1];  // y_pred
    float* out = (float*)d_out;

    const size_t needA = (size_t)5 * B_ * DHW_ * sizeof(float);  // 196.6 MB
    if (ws_size >= 1024 + needA) {
        double* acc = (double*)d_ws;
        float* A = (float*)((char*)d_ws + 1024);
        k_zero<<<1, 1, 0, stream>>>(acc);
        const int ncol = B_ * D_ * NYC * W4_;
        k1_ysum<<<(ncol + 255) / 256, 256, 0, stream>>>(I, J, A);
        k2_zxcc<<<NZC2 * (B_ * H_ / ROWS2), ROWS2 * W4_, 0, stream>>>(A, acc);
        k_final<<<1, 1, 0, stream>>>(acc, out);
    } else if (ws_size >= sizeof(double)) {
        double* acc = (double*)d_ws;
        k_zero<<<1, 1, 0, stream>>>(acc);
        p_direct<<<(int)((NV_ + 255) / 256), 256, 0, stream>>>(I, J, acc);
        k_final<<<1, 1, 0, stream>>>(acc, out);
    }
}

// Round 7
// 123.553 us; speedup vs baseline: 6.6156x; 1.3052x over previous
//
#include <hip/hip_runtime.h>

// Shape: (B=2, C=1, D=160, H=192, W=160) fp32. win=9/dim, win_size=9 (faithful bug).
#define B_ 2
#define D_ 160
#define H_ 192
#define W_ 160
#define W4_ (W_ / 4)                         // 40
#define HW_ (H_ * W_)                        // 30720
#define DHW_ (D_ * HW_)                      // 4,915,200
#define NV_ ((long long)B_ * D_ * H_ * W_)   // 9,830,400

#define YCH 12
#define NYC (H_ / YCH)     // 16

#define ROWS2 8
#define ZCH2 10
#define NZC2 (D_ / ZCH2)   // 16
#define PAD 4
#define LROW (W_ + 2 * PAD)  // 168

typedef _Float16 half4 __attribute__((ext_vector_type(4)));

__global__ void k_zero(double* acc) { *acc = 0.0; }

__device__ __forceinline__ void add4h(float4& d, const half4 v) {
    d.x += (float)v.x; d.y += (float)v.y; d.z += (float)v.z; d.w += (float)v.w;
}
__device__ __forceinline__ void sub4h(float4& d, const half4 v) {
    d.x -= (float)v.x; d.y -= (float)v.y; d.z -= (float)v.z; d.w -= (float)v.w;
}

// ---------------------------------------------------------------------------
// K1: y-direction 9-window sums of the 5 product maps, float4 along x,
// stored to A as fp16 (half4). One thread per (b, z, y-chunk, x4).
// A layout: [(b*5+c)*D + z][y][x] in _Float16.
// ---------------------------------------------------------------------------
__global__ void k1_ysum(const float* __restrict__ I, const float* __restrict__ J,
                        _Float16* __restrict__ A) {
    const int g = blockIdx.x * blockDim.x + threadIdx.x;
    const int ncol = B_ * D_ * NYC * W4_;    // 204,800
    if (g >= ncol) return;
    const int l  = g % W4_;
    int t = g / W4_;
    const int yc = t % NYC;  t /= NYC;
    const int z  = t % D_;
    const int b  = t / D_;
    const int y0 = yc * YCH;
    const int x4 = l * 4;

    const float* Ipf = I + ((size_t)(b * D_ + z) * H_) * W_ + x4;
    const float* Jpf = J + ((size_t)(b * D_ + z) * H_) * W_ + x4;
    _Float16* Ap = A + (size_t)(b * 5) * DHW_ + (size_t)z * HW_ + x4;

    float4 s0 = make_float4(0,0,0,0), s1 = s0, s2 = s0, s3 = s0, s4 = s0;
#pragma unroll
    for (int j = 0; j < 8; ++j) {            // prime window [y0-4, y0+3]
        const int yin = y0 - 4 + j;          // yin <= y0+3 <= 183 < H_ always
        if (yin >= 0) {
            const float4 a  = *(const float4*)(Ipf + (size_t)yin * W_);
            const float4 bb = *(const float4*)(Jpf + (size_t)yin * W_);
            s0.x += a.x;        s0.y += a.y;        s0.z += a.z;        s0.w += a.w;
            s1.x += bb.x;       s1.y += bb.y;       s1.z += bb.z;       s1.w += bb.w;
            s2.x += a.x*a.x;    s2.y += a.y*a.y;    s2.z += a.z*a.z;    s2.w += a.w*a.w;
            s3.x += bb.x*bb.x;  s3.y += bb.y*bb.y;  s3.z += bb.z*bb.z;  s3.w += bb.w*bb.w;
            s4.x += a.x*bb.x;   s4.y += a.y*bb.y;   s4.z += a.z*bb.z;   s4.w += a.w*bb.w;
        }
    }
#pragma unroll 4
    for (int k = 0; k < YCH; ++k) {
        const int yi = y0 + k + 4;           // leading edge
        if (yi < H_) {
            const float4 a  = *(const float4*)(Ipf + (size_t)yi * W_);
            const float4 bb = *(const float4*)(Jpf + (size_t)yi * W_);
            s0.x += a.x;        s0.y += a.y;        s0.z += a.z;        s0.w += a.w;
            s1.x += bb.x;       s1.y += bb.y;       s1.z += bb.z;       s1.w += bb.w;
            s2.x += a.x*a.x;    s2.y += a.y*a.y;    s2.z += a.z*a.z;    s2.w += a.w*a.w;
            s3.x += bb.x*bb.x;  s3.y += bb.y*bb.y;  s3.z += bb.z*bb.z;  s3.w += bb.w*bb.w;
            s4.x += a.x*bb.x;   s4.y += a.y*bb.y;   s4.z += a.z*bb.z;   s4.w += a.w*bb.w;
        }
        const int yo = y0 + k - 5;           // trailing edge
        if (yo >= 0) {
            const float4 a  = *(const float4*)(Ipf + (size_t)yo * W_);
            const float4 bb = *(const float4*)(Jpf + (size_t)yo * W_);
            s0.x -= a.x;        s0.y -= a.y;        s0.z -= a.z;        s0.w -= a.w;
            s1.x -= bb.x;       s1.y -= bb.y;       s1.z -= bb.z;       s1.w -= bb.w;
            s2.x -= a.x*a.x;    s2.y -= a.y*a.y;    s2.z -= a.z*a.z;    s2.w -= a.w*a.w;
            s3.x -= bb.x*bb.x;  s3.y -= bb.y*bb.y;  s3.z -= bb.z*bb.z;  s3.w -= bb.w*bb.w;
            s4.x -= a.x*bb.x;   s4.y -= a.y*bb.y;   s4.z -= a.z*bb.z;   s4.w -= a.w*bb.w;
        }
        const size_t o = (size_t)(y0 + k) * W_;
        half4 h0, h1, h2, h3, h4;
        h0.x = (_Float16)s0.x; h0.y = (_Float16)s0.y; h0.z = (_Float16)s0.z; h0.w = (_Float16)s0.w;
        h1.x = (_Float16)s1.x; h1.y = (_Float16)s1.y; h1.z = (_Float16)s1.z; h1.w = (_Float16)s1.w;
        h2.x = (_Float16)s2.x; h2.y = (_Float16)s2.y; h2.z = (_Float16)s2.z; h2.w = (_Float16)s2.w;
        h3.x = (_Float16)s3.x; h3.y = (_Float16)s3.y; h3.z = (_Float16)s3.z; h3.w = (_Float16)s3.w;
        h4.x = (_Float16)s4.x; h4.y = (_Float16)s4.y; h4.z = (_Float16)s4.z; h4.w = (_Float16)s4.w;
        *(half4*)(Ap + o)                      = h0;
        *(half4*)(Ap + o + 1 * (size_t)DHW_)   = h1;
        *(half4*)(Ap + o + 2 * (size_t)DHW_)   = h2;
        *(half4*)(Ap + o + 3 * (size_t)DHW_)   = h3;
        *(half4*)(Ap + o + 4 * (size_t)DHW_)   = h4;
    }
}

// ---------------------------------------------------------------------------
// K2: fused z-window sum (fp32 running sums over fp16 A) + x-window
// (3x ds_read_b128 per channel over a padded LDS row) + cc + reduction.
// Block = 8 rows x 40 lanes (320 thr); each thread owns 4 x-columns and
// marches a z-chunk of 10. One barrier per z-step (double-buffered LDS).
// ---------------------------------------------------------------------------
__global__ void k2_zxcc(const _Float16* __restrict__ A, double* __restrict__ acc) {
    __shared__ float sbuf[2][ROWS2][5][LROW];   // 53.76 KB
    __shared__ float red[512];
    const int tid = threadIdx.x;             // 0..319
    const int r   = tid / W4_;               // 0..7
    const int l   = tid - r * W4_;           // 0..39
    const int x4  = l * 4;
    const int blk = blockIdx.x;
    const int zc  = blk % NZC2;
    const int rp  = blk / NZC2;              // 0..47
    const int gy  = rp * ROWS2 + r;          // 0..383  (192%8==0: no b straddle)
    const int b   = gy / H_;
    const int yy  = gy - b * H_;
    const int z0  = zc * ZCH2;

    {   // zero LDS once (pads must be 0; interior overwritten every step)
        float* p = &sbuf[0][0][0][0];
        for (int i = tid; i < 2 * ROWS2 * 5 * LROW; i += ROWS2 * W4_) p[i] = 0.f;
    }
    __syncthreads();

    const _Float16* Abase = A + (size_t)(b * 5) * DHW_ + (size_t)yy * W_ + x4;

    float4 s[5];
#pragma unroll
    for (int c = 0; c < 5; ++c) s[c] = make_float4(0, 0, 0, 0);
#pragma unroll
    for (int j = 0; j < 8; ++j) {            // prime [z0-4, z0+3]; z0+3 <= 153 < D_
        const int zi = z0 - 4 + j;
        if (zi >= 0) {
#pragma unroll
            for (int c = 0; c < 5; ++c)
                add4h(s[c], *(const half4*)(Abase + (size_t)c * DHW_ + (size_t)zi * HW_));
        }
    }

    float local = 0.f;
    for (int k = 0; k < ZCH2; ++k) {
        const int zi = z0 + k + 4;
        if (zi < D_) {
#pragma unroll
            for (int c = 0; c < 5; ++c)
                add4h(s[c], *(const half4*)(Abase + (size_t)c * DHW_ + (size_t)zi * HW_));
        }
        const int zo = z0 + k - 5;
        if (zo >= 0) {
#pragma unroll
            for (int c = 0; c < 5; ++c)
                sub4h(s[c], *(const half4*)(Abase + (size_t)c * DHW_ + (size_t)zo * HW_));
        }
        const int p = k & 1;
#pragma unroll
        for (int c = 0; c < 5; ++c)
            *(float4*)&sbuf[p][r][c][PAD + x4] = s[c];
        __syncthreads();

        float4 S5[5];
#pragma unroll
        for (int c = 0; c < 5; ++c) {
            // storage index of x-window start (x4-4) is PAD + x4 - 4 = x4: aligned.
            const float4 a0 = *(const float4*)&sbuf[p][r][c][x4];
            const float4 a1 = *(const float4*)&sbuf[p][r][c][x4 + 4];
            const float4 a2 = *(const float4*)&sbuf[p][r][c][x4 + 8];
            const float o0 = a0.x + a0.y + a0.z + a0.w + a1.x + a1.y + a1.z + a1.w + a2.x;
            const float o1 = o0 - a0.x + a2.y;
            const float o2 = o1 - a0.y + a2.z;
            const float o3 = o2 - a0.z + a2.w;
            S5[c] = make_float4(o0, o1, o2, o3);
        }
        const float inv9 = 1.0f / 9.0f;
        {
            const float cr = S5[4].x - S5[1].x * S5[0].x * inv9;
            const float iv = S5[2].x - S5[0].x * S5[0].x * inv9;
            const float jv = S5[3].x - S5[1].x * S5[1].x * inv9;
            local += cr * cr / (iv * jv + 1e-5f);
        }
        {
            const float cr = S5[4].y - S5[1].y * S5[0].y * inv9;
            const float iv = S5[2].y - S5[0].y * S5[0].y * inv9;
            const float jv = S5[3].y - S5[1].y * S5[1].y * inv9;
            local += cr * cr / (iv * jv + 1e-5f);
        }
        {
            const float cr = S5[4].z - S5[1].z * S5[0].z * inv9;
            const float iv = S5[2].z - S5[0].z * S5[0].z * inv9;
            const float jv = S5[3].z - S5[1].z * S5[1].z * inv9;
            local += cr * cr / (iv * jv + 1e-5f);
        }
        {
            const float cr = S5[4].w - S5[1].w * S5[0].w * inv9;
            const float iv = S5[2].w - S5[0].w * S5[0].w * inv9;
            const float jv = S5[3].w - S5[1].w * S5[1].w * inv9;
            local += cr * cr / (iv * jv + 1e-5f);
        }
        // single barrier per step is WAR-safe: next iteration writes buffer p^1.
    }

    red[tid] = local;
    if (tid < 192) red[320 + tid] = 0.f;
    __syncthreads();
    for (int off = 256; off > 0; off >>= 1) {
        if (tid < off) red[tid] += red[tid + off];
        __syncthreads();
    }
    if (tid == 0) atomicAdd(acc, (double)red[0]);
}

// ---------------------------------------------------------------------------
// Fallback (workspace too small): direct clipped 9x9x9 sums per voxel.
// ---------------------------------------------------------------------------
__global__ void p_direct(const float* __restrict__ I, const float* __restrict__ J,
                         double* __restrict__ acc) {
    const long long idx = (long long)blockIdx.x * blockDim.x + threadIdx.x;
    float local = 0.f;
    if (idx < NV_) {
        const int x = (int)(idx % W_);
        long long t = idx / W_;
        const int y = (int)(t % H_);
        t /= H_;
        const int z = (int)(t % D_);
        const int b = (int)(t / D_);
        const int z0 = max(z - 4, 0), z1 = min(z + 4, D_ - 1);
        const int y0 = max(y - 4, 0), y1 = min(y + 4, H_ - 1);
        const int x0 = max(x - 4, 0), x1 = min(x + 4, W_ - 1);
        float sI = 0.f, sJ = 0.f, sI2 = 0.f, sJ2 = 0.f, sIJ = 0.f;
        for (int zz = z0; zz <= z1; ++zz)
            for (int yy = y0; yy <= y1; ++yy) {
                const size_t row = ((size_t)(b * D_ + zz) * H_ + yy) * W_;
                for (int xx = x0; xx <= x1; ++xx) {
                    const float a = I[row + xx];
                    const float bb = J[row + xx];
                    sI += a; sJ += bb; sI2 += a * a; sJ2 += bb * bb; sIJ += a * bb;
                }
            }
        const float inv9 = 1.0f / 9.0f;
        const float cross = sIJ - sJ * sI * inv9;
        const float iv    = sI2 - sI * sI * inv9;
        const float jv    = sJ2 - sJ * sJ * inv9;
        local = cross * cross / (iv * jv + 1e-5f);
    }
    __shared__ float red[256];
    red[threadIdx.x] = local;
    __syncthreads();
    for (int off = 128; off > 0; off >>= 1) {
        if (threadIdx.x < off) red[threadIdx.x] += red[threadIdx.x + off];
        __syncthreads();
    }
    if (threadIdx.x == 0) atomicAdd(acc, (double)red[0]);
}

__global__ void k_final(const double* __restrict__ acc, float* __restrict__ out) {
    out[0] = (float)(-(*acc) / (double)NV_);
}

extern "C" void kernel_launch(void* const* d_in, const int* in_sizes, int n_in,
                              void* d_out, int out_size, void* d_ws, size_t ws_size,
                              hipStream_t stream) {
    const float* I = (const float*)d_in[0];  // y_true
    const float* J = (const float*)d_in[1];  // y_pred
    float* out = (float*)d_out;

    const size_t needA = (size_t)5 * B_ * DHW_ * sizeof(_Float16);  // 98.3 MB
    if (ws_size >= 1024 + needA) {
        double* acc = (double*)d_ws;
        _Float16* A = (_Float16*)((char*)d_ws + 1024);
        k_zero<<<1, 1, 0, stream>>>(acc);
        const int ncol = B_ * D_ * NYC * W4_;
        k1_ysum<<<(ncol + 255) / 256, 256, 0, stream>>>(I, J, A);
        k2_zxcc<<<NZC2 * (B_ * H_ / ROWS2), ROWS2 * W4_, 0, stream>>>(A, acc);
        k_final<<<1, 1, 0, stream>>>(acc, out);
    } else if (ws_size >= sizeof(double)) {
        double* acc = (double*)d_ws;
        k_zero<<<1, 1, 0, stream>>>(acc);
        p_direct<<<(int)((NV_ + 255) / 256), 256, 0, stream>>>(I, J, acc);
        k_final<<<1, 1, 0, stream>>>(acc, out);
    }
}

// Round 8
// 109.679 us; speedup vs baseline: 7.4525x; 1.1265x over previous
//
#include <hip/hip_runtime.h>

// Shape: (B=2, C=1, D=160, H=192, W=160) fp32. win=9/dim, win_size=9 (faithful bug).
#define B_ 2
#define D_ 160
#define H_ 192
#define W_ 160
#define W4_ (W_ / 4)                         // 40
#define HW_ (H_ * W_)                        // 30720
#define DHW_ (D_ * HW_)                      // 4,915,200
#define NV_ ((long long)B_ * D_ * H_ * W_)   // 9,830,400

#define YCH 6
#define NYC (H_ / YCH)     // 32

#define ROWS2 8
#define ZCH2 10
#define NZC2 (D_ / ZCH2)   // 16
#define PAD 4
#define LROW (W_ + 2 * PAD)  // 168

typedef _Float16 half4 __attribute__((ext_vector_type(4)));

__global__ void k_zero(double* acc) { *acc = 0.0; }

__device__ __forceinline__ void add4h(float4& d, const half4 v) {
    d.x += (float)v.x; d.y += (float)v.y; d.z += (float)v.z; d.w += (float)v.w;
}
__device__ __forceinline__ void sub4h(float4& d, const half4 v) {
    d.x -= (float)v.x; d.y -= (float)v.y; d.z -= (float)v.z; d.w -= (float)v.w;
}

// ---------------------------------------------------------------------------
// K1: y-direction 9-window sums of the 5 product maps, float4 along x,
// stored to A as fp16 (half4). One thread per (b, z, y-chunk, x4).
// A layout: [(b*5+c)*D + z][y][x] in _Float16.
// ---------------------------------------------------------------------------
__global__ void k1_ysum(const float* __restrict__ I, const float* __restrict__ J,
                        _Float16* __restrict__ A) {
    const int g = blockIdx.x * blockDim.x + threadIdx.x;
    const int ncol = B_ * D_ * NYC * W4_;    // 409,600
    if (g >= ncol) return;
    const int l  = g % W4_;
    int t = g / W4_;
    const int yc = t % NYC;  t /= NYC;
    const int z  = t % D_;
    const int b  = t / D_;
    const int y0 = yc * YCH;
    const int x4 = l * 4;

    const float* Ipf = I + ((size_t)(b * D_ + z) * H_) * W_ + x4;
    const float* Jpf = J + ((size_t)(b * D_ + z) * H_) * W_ + x4;
    _Float16* Ap = A + (size_t)(b * 5) * DHW_ + (size_t)z * HW_ + x4;

    float4 s0 = make_float4(0,0,0,0), s1 = s0, s2 = s0, s3 = s0, s4 = s0;
#pragma unroll
    for (int j = 0; j < 8; ++j) {            // prime window [y0-4, y0+3]
        const int yin = y0 - 4 + j;          // yin <= y0+3 <= 189 < H_ always
        if (yin >= 0) {
            const float4 a  = *(const float4*)(Ipf + (size_t)yin * W_);
            const float4 bb = *(const float4*)(Jpf + (size_t)yin * W_);
            s0.x += a.x;        s0.y += a.y;        s0.z += a.z;        s0.w += a.w;
            s1.x += bb.x;       s1.y += bb.y;       s1.z += bb.z;       s1.w += bb.w;
            s2.x += a.x*a.x;    s2.y += a.y*a.y;    s2.z += a.z*a.z;    s2.w += a.w*a.w;
            s3.x += bb.x*bb.x;  s3.y += bb.y*bb.y;  s3.z += bb.z*bb.z;  s3.w += bb.w*bb.w;
            s4.x += a.x*bb.x;   s4.y += a.y*bb.y;   s4.z += a.z*bb.z;   s4.w += a.w*bb.w;
        }
    }
#pragma unroll
    for (int k = 0; k < YCH; ++k) {
        const int yi = y0 + k + 4;           // leading edge
        if (yi < H_) {
            const float4 a  = *(const float4*)(Ipf + (size_t)yi * W_);
            const float4 bb = *(const float4*)(Jpf + (size_t)yi * W_);
            s0.x += a.x;        s0.y += a.y;        s0.z += a.z;        s0.w += a.w;
            s1.x += bb.x;       s1.y += bb.y;       s1.z += bb.z;       s1.w += bb.w;
            s2.x += a.x*a.x;    s2.y += a.y*a.y;    s2.z += a.z*a.z;    s2.w += a.w*a.w;
            s3.x += bb.x*bb.x;  s3.y += bb.y*bb.y;  s3.z += bb.z*bb.z;  s3.w += bb.w*bb.w;
            s4.x += a.x*bb.x;   s4.y += a.y*bb.y;   s4.z += a.z*bb.z;   s4.w += a.w*bb.w;
        }
        const int yo = y0 + k - 5;           // trailing edge
        if (yo >= 0) {
            const float4 a  = *(const float4*)(Ipf + (size_t)yo * W_);
            const float4 bb = *(const float4*)(Jpf + (size_t)yo * W_);
            s0.x -= a.x;        s0.y -= a.y;        s0.z -= a.z;        s0.w -= a.w;
            s1.x -= bb.x;       s1.y -= bb.y;       s1.z -= bb.z;       s1.w -= bb.w;
            s2.x -= a.x*a.x;    s2.y -= a.y*a.y;    s2.z -= a.z*a.z;    s2.w -= a.w*a.w;
            s3.x -= bb.x*bb.x;  s3.y -= bb.y*bb.y;  s3.z -= bb.z*bb.z;  s3.w -= bb.w*bb.w;
            s4.x -= a.x*bb.x;   s4.y -= a.y*bb.y;   s4.z -= a.z*bb.z;   s4.w -= a.w*bb.w;
        }
        const size_t o = (size_t)(y0 + k) * W_;
        half4 h0, h1, h2, h3, h4;
        h0.x = (_Float16)s0.x; h0.y = (_Float16)s0.y; h0.z = (_Float16)s0.z; h0.w = (_Float16)s0.w;
        h1.x = (_Float16)s1.x; h1.y = (_Float16)s1.y; h1.z = (_Float16)s1.z; h1.w = (_Float16)s1.w;
        h2.x = (_Float16)s2.x; h2.y = (_Float16)s2.y; h2.z = (_Float16)s2.z; h2.w = (_Float16)s2.w;
        h3.x = (_Float16)s3.x; h3.y = (_Float16)s3.y; h3.z = (_Float16)s3.z; h3.w = (_Float16)s3.w;
        h4.x = (_Float16)s4.x; h4.y = (_Float16)s4.y; h4.z = (_Float16)s4.z; h4.w = (_Float16)s4.w;
        *(half4*)(Ap + o)                      = h0;
        *(half4*)(Ap + o + 1 * (size_t)DHW_)   = h1;
        *(half4*)(Ap + o + 2 * (size_t)DHW_)   = h2;
        *(half4*)(Ap + o + 3 * (size_t)DHW_)   = h3;
        *(half4*)(Ap + o + 4 * (size_t)DHW_)   = h4;
    }
}

// ---------------------------------------------------------------------------
// K2: fused z-window sum (fp32 running sums over fp16 A) + x-window
// (3x ds_read_b128 per channel over a padded LDS row) + cc + reduction.
// Block = 8 rows x 40 lanes (320 thr); thread owns 4 x-columns, marches a
// z-chunk of 10. SINGLE-buffered LDS (write/barrier/read/barrier) so the
// block fits 5x per CU (28.9 KB) instead of 2x (55.8 KB).
// ---------------------------------------------------------------------------
__global__ void k2_zxcc(const _Float16* __restrict__ A, double* __restrict__ acc) {
    __shared__ float sbuf[ROWS2][5][LROW];   // 26.88 KB
    __shared__ float red[512];
    const int tid = threadIdx.x;             // 0..319
    const int r   = tid / W4_;               // 0..7
    const int l   = tid - r * W4_;           // 0..39
    const int x4  = l * 4;
    const int blk = blockIdx.x;
    const int zc  = blk % NZC2;
    const int rp  = blk / NZC2;              // 0..47
    const int gy  = rp * ROWS2 + r;          // 0..383  (192%8==0: no b straddle)
    const int b   = gy / H_;
    const int yy  = gy - b * H_;
    const int z0  = zc * ZCH2;

    {   // zero LDS once (pads must be 0; interior overwritten every step)
        float* p = &sbuf[0][0][0];
        for (int i = tid; i < ROWS2 * 5 * LROW; i += ROWS2 * W4_) p[i] = 0.f;
    }

    const _Float16* Abase = A + (size_t)(b * 5) * DHW_ + (size_t)yy * W_ + x4;

    float4 s[5];
#pragma unroll
    for (int c = 0; c < 5; ++c) s[c] = make_float4(0, 0, 0, 0);
#pragma unroll
    for (int j = 0; j < 8; ++j) {            // prime [z0-4, z0+3]; z0+3 <= 153 < D_
        const int zi = z0 - 4 + j;
        if (zi >= 0) {
#pragma unroll
            for (int c = 0; c < 5; ++c)
                add4h(s[c], *(const half4*)(Abase + (size_t)c * DHW_ + (size_t)zi * HW_));
        }
    }
    __syncthreads();                         // LDS zero visible

    float local = 0.f;
    for (int k = 0; k < ZCH2; ++k) {
        const int zi = z0 + k + 4;
        if (zi < D_) {
#pragma unroll
            for (int c = 0; c < 5; ++c)
                add4h(s[c], *(const half4*)(Abase + (size_t)c * DHW_ + (size_t)zi * HW_));
        }
        const int zo = z0 + k - 5;
        if (zo >= 0) {
#pragma unroll
            for (int c = 0; c < 5; ++c)
                sub4h(s[c], *(const half4*)(Abase + (size_t)c * DHW_ + (size_t)zo * HW_));
        }
#pragma unroll
        for (int c = 0; c < 5; ++c)
            *(float4*)&sbuf[r][c][PAD + x4] = s[c];
        __syncthreads();

        float4 S5[5];
#pragma unroll
        for (int c = 0; c < 5; ++c) {
            // storage index of x-window start (x4-4) is PAD + x4 - 4 = x4: aligned.
            const float4 a0 = *(const float4*)&sbuf[r][c][x4];
            const float4 a1 = *(const float4*)&sbuf[r][c][x4 + 4];
            const float4 a2 = *(const float4*)&sbuf[r][c][x4 + 8];
            const float o0 = a0.x + a0.y + a0.z + a0.w + a1.x + a1.y + a1.z + a1.w + a2.x;
            const float o1 = o0 - a0.x + a2.y;
            const float o2 = o1 - a0.y + a2.z;
            const float o3 = o2 - a0.z + a2.w;
            S5[c] = make_float4(o0, o1, o2, o3);
        }
        const float inv9 = 1.0f / 9.0f;
        {
            const float cr = S5[4].x - S5[1].x * S5[0].x * inv9;
            const float iv = S5[2].x - S5[0].x * S5[0].x * inv9;
            const float jv = S5[3].x - S5[1].x * S5[1].x * inv9;
            local += cr * cr / (iv * jv + 1e-5f);
        }
        {
            const float cr = S5[4].y - S5[1].y * S5[0].y * inv9;
            const float iv = S5[2].y - S5[0].y * S5[0].y * inv9;
            const float jv = S5[3].y - S5[1].y * S5[1].y * inv9;
            local += cr * cr / (iv * jv + 1e-5f);
        }
        {
            const float cr = S5[4].z - S5[1].z * S5[0].z * inv9;
            const float iv = S5[2].z - S5[0].z * S5[0].z * inv9;
            const float jv = S5[3].z - S5[1].z * S5[1].z * inv9;
            local += cr * cr / (iv * jv + 1e-5f);
        }
        {
            const float cr = S5[4].w - S5[1].w * S5[0].w * inv9;
            const float iv = S5[2].w - S5[0].w * S5[0].w * inv9;
            const float jv = S5[3].w - S5[1].w * S5[1].w * inv9;
            local += cr * cr / (iv * jv + 1e-5f);
        }
        __syncthreads();                     // WAR: next step overwrites sbuf
    }

    red[tid] = local;
    if (tid < 192) red[320 + tid] = 0.f;
    __syncthreads();
    for (int off = 256; off > 0; off >>= 1) {
        if (tid < off) red[tid] += red[tid + off];
        __syncthreads();
    }
    if (tid == 0) atomicAdd(acc, (double)red[0]);
}

// ---------------------------------------------------------------------------
// Fallback (workspace too small): direct clipped 9x9x9 sums per voxel.
// ---------------------------------------------------------------------------
__global__ void p_direct(const float* __restrict__ I, const float* __restrict__ J,
                         double* __restrict__ acc) {
    const long long idx = (long long)blockIdx.x * blockDim.x + threadIdx.x;
    float local = 0.f;
    if (idx < NV_) {
        const int x = (int)(idx % W_);
        long long t = idx / W_;
        const int y = (int)(t % H_);
        t /= H_;
        const int z = (int)(t % D_);
        const int b = (int)(t / D_);
        const int z0 = max(z - 4, 0), z1 = min(z + 4, D_ - 1);
        const int y0 = max(y - 4, 0), y1 = min(y + 4, H_ - 1);
        const int x0 = max(x - 4, 0), x1 = min(x + 4, W_ - 1);
        float sI = 0.f, sJ = 0.f, sI2 = 0.f, sJ2 = 0.f, sIJ = 0.f;
        for (int zz = z0; zz <= z1; ++zz)
            for (int yy = y0; yy <= y1; ++yy) {
                const size_t row = ((size_t)(b * D_ + zz) * H_ + yy) * W_;
                for (int xx = x0; xx <= x1; ++xx) {
                    const float a = I[row + xx];
                    const float bb = J[row + xx];
                    sI += a; sJ += bb; sI2 += a * a; sJ2 += bb * bb; sIJ += a * bb;
                }
            }
        const float inv9 = 1.0f / 9.0f;
        const float cross = sIJ - sJ * sI * inv9;
        const float iv    = sI2 - sI * sI * inv9;
        const float jv    = sJ2 - sJ * sJ * inv9;
        local = cross * cross / (iv * jv + 1e-5f);
    }
    __shared__ float red[256];
    red[threadIdx.x] = local;
    __syncthreads();
    for (int off = 128; off > 0; off >>= 1) {
        if (threadIdx.x < off) red[threadIdx.x] += red[threadIdx.x + off];
        __syncthreads();
    }
    if (threadIdx.x == 0) atomicAdd(acc, (double)red[0]);
}

__global__ void k_final(const double* __restrict__ acc, float* __restrict__ out) {
    out[0] = (float)(-(*acc) / (double)NV_);
}

extern "C" void kernel_launch(void* const* d_in, const int* in_sizes, int n_in,
                              void* d_out, int out_size, void* d_ws, size_t ws_size,
                              hipStream_t stream) {
    const float* I = (const float*)d_in[0];  // y_true
    const float* J = (const float*)d_in[1];  // y_pred
    float* out = (float*)d_out;

    const size_t needA = (size_t)5 * B_ * DHW_ * sizeof(_Float16);  // 98.3 MB
    if (ws_size >= 1024 + needA) {
        double* acc = (double*)d_ws;
        _Float16* A = (_Float16*)((char*)d_ws + 1024);
        k_zero<<<1, 1, 0, stream>>>(acc);
        const int ncol = B_ * D_ * NYC * W4_;
        k1_ysum<<<(ncol + 255) / 256, 256, 0, stream>>>(I, J, A);
        k2_zxcc<<<NZC2 * (B_ * H_ / ROWS2), ROWS2 * W4_, 0, stream>>>(A, acc);
        k_final<<<1, 1, 0, stream>>>(acc, out);
    } else if (ws_size >= sizeof(double)) {
        double* acc = (double*)d_ws;
        k_zero<<<1, 1, 0, stream>>>(acc);
        p_direct<<<(int)((NV_ + 255) / 256), 256, 0, stream>>>(I, J, acc);
        k_final<<<1, 1, 0, stream>>>(acc, out);
    }
}